// Round 5
// baseline (188.891 us; speedup 1.0000x reference)
//
#include <hip/hip_runtime.h>
#include <hip/hip_bf16.h>
#include <stdint.h>

#define BB 16
#define NN 4096
#define MM 1024
#define C1 128
#define C2 256
#define CIN 384
#define CO 256
#define ROWS (BB * NN)

typedef __attribute__((ext_vector_type(8))) short bf16x8;
typedef __attribute__((ext_vector_type(4))) float f32x4;

__device__ inline float u2f(uint32_t u) { union { uint32_t u; float f; } v; v.u = u; return v.f; }
__device__ inline uint32_t f2u(float f) { union { float f; uint32_t u; } v; v.f = f; return v.u; }
// round-to-nearest-even f32 -> bf16
__device__ inline unsigned short f2bf(float f) {
  uint32_t u = f2u(f);
  uint32_t r = u + 0x7fffu + ((u >> 16) & 1u);
  return (unsigned short)(r >> 16);
}
__device__ inline float bflo(uint32_t w) { return u2f(w << 16); }
__device__ inline float bfhi(uint32_t w) { return u2f(w & 0xffff0000u); }

// ---------------------------------------------------------------- three_nn
#define NN_INS(dd, jj_)                                        \
  {                                                            \
    bool c0 = (dd) < e0, c1 = (dd) < e1, c2 = (dd) < e2;       \
    e2 = c2 ? (c1 ? e1 : (dd)) : e2;                           \
    i2 = c2 ? (c1 ? i1 : (jj_)) : i2;                          \
    e1 = c1 ? (c0 ? e0 : (dd)) : e1;                           \
    i1 = c1 ? (c0 ? i0 : (jj_)) : i1;                          \
    e0 = c0 ? (dd) : e0;                                       \
    i0 = c0 ? (jj_) : i0;                                      \
  }

__global__ __launch_bounds__(256) void nn_kernel(const float* __restrict__ xyz1,
                                                 const float* __restrict__ xyz2,
                                                 int* __restrict__ idx,
                                                 float* __restrict__ wgt) {
  __shared__ float4 q[MM];  // 16 KB
  int b = blockIdx.x >> 7;                 // 128 blocks per batch (N/32)
  int qbase = (blockIdx.x & 127) << 5;     // 32 queries per block
  const float* x2 = xyz2 + (size_t)b * MM * 3;
  for (int j = threadIdx.x; j < MM; j += 256)
    q[j] = make_float4(x2[j * 3 + 0], x2[j * 3 + 1], x2[j * 3 + 2], 0.f);
  __syncthreads();
  int n = qbase + (threadIdx.x >> 3);
  int tq = threadIdx.x & 7;
  const float* p = xyz1 + ((size_t)b * NN + n) * 3;
  float px = p[0], py = p[1], pz = p[2];
  float e0 = 1e30f, e1 = 1e30f, e2 = 1e30f;
  int i0 = 0, i1 = 0, i2 = 0;
#pragma unroll 8
  for (int jj = 0; jj < MM / 8; ++jj) {
    int j = jj * 8 + tq;
    float4 qv = q[j];
    float dx = px - qv.x, dy = py - qv.y, dz = pz - qv.z;
    float d = dx * dx + dy * dy + dz * dz;
    NN_INS(d, j);
  }
#pragma unroll
  for (int mk = 1; mk <= 4; mk <<= 1) {
    float f0 = __shfl_xor(e0, mk), f1 = __shfl_xor(e1, mk), f2 = __shfl_xor(e2, mk);
    int j0 = __shfl_xor(i0, mk), j1 = __shfl_xor(i1, mk), j2 = __shfl_xor(i2, mk);
    NN_INS(f0, j0);
    NN_INS(f1, j1);
    NN_INS(f2, j2);
  }
  if (tq == 0) {
    float a0 = fmaxf(e0, 1e-10f), a1 = fmaxf(e1, 1e-10f), a2 = fmaxf(e2, 1e-10f);
    float v0 = 1.f / a0, v1 = 1.f / a1, v2 = 1.f / a2;
    float inv = 1.f / (v0 + v1 + v2);
    size_t base = ((size_t)b * NN + n) * 3;
    idx[base + 0] = i0; idx[base + 1] = i1; idx[base + 2] = i2;
    wgt[base + 0] = v0 * inv; wgt[base + 1] = v1 * inv; wgt[base + 2] = v2 * inv;
  }
}

// -------------------------------------------- interpolate + concat -> x bf16
__global__ __launch_bounds__(256) void interp_kernel(const float* __restrict__ points2,
                                                     const float* __restrict__ points1,
                                                     const int* __restrict__ idx,
                                                     const float* __restrict__ wgt,
                                                     unsigned short* __restrict__ X) {
  int row = blockIdx.x * 2 + (threadIdx.x >> 7);
  int t = threadIdx.x & 127;
  int b = row >> 12;  // N = 4096 rows per batch
  unsigned short* xr = X + (size_t)row * CIN;
  if (t < 64) {
    const int* id = idx + (size_t)row * 3;
    const float* w = wgt + (size_t)row * 3;
    const float* p2 = points2 + (size_t)b * MM * C2 + t * 4;
    float w0 = w[0], w1 = w[1], w2 = w[2];
    float4 a0 = *(const float4*)(p2 + (size_t)id[0] * C2);
    float4 a1 = *(const float4*)(p2 + (size_t)id[1] * C2);
    float4 a2 = *(const float4*)(p2 + (size_t)id[2] * C2);
    ushort4 o;
    o.x = f2bf(w0 * a0.x + w1 * a1.x + w2 * a2.x);
    o.y = f2bf(w0 * a0.y + w1 * a1.y + w2 * a2.y);
    o.z = f2bf(w0 * a0.z + w1 * a1.z + w2 * a2.z);
    o.w = f2bf(w0 * a0.w + w1 * a1.w + w2 * a2.w);
    *(ushort4*)(xr + t * 4) = o;
  } else if (t < 96) {
    int c = (t - 64) * 4;
    float4 a = *(const float4*)(points1 + (size_t)row * C1 + c);
    ushort4 o;
    o.x = f2bf(a.x); o.y = f2bf(a.y); o.z = f2bf(a.z); o.w = f2bf(a.w);
    *(ushort4*)(xr + C2 + c) = o;
  }
}

// ------------------------------------- weight convert + transpose: Wt[n][k]
// Also zeroes this layer's 512-float stats slice (block 0).
__global__ __launch_bounds__(256) void wt_kernel(const float* __restrict__ W,
                                                 unsigned short* __restrict__ Wt,
                                                 int K, int Nc, float* __restrict__ stats) {
  int t = threadIdx.x;
  if (blockIdx.x == 0) { stats[t] = 0.f; stats[256 + t] = 0.f; }
  int i = blockIdx.x * 256 + t;
  if (i >= K * Nc) return;
  int n = i / K, k = i - n * K;
  Wt[i] = f2bf(W[(size_t)k * Nc + n]);
}

// ---------------------------------------------------------------- bf16 GEMM
// C[m][n] = sum_k A'[m][k] * Bt[n][k];  A' = FUSE ? relu(A*sc+sh) : A.
// m97 template + T2 swizzle: global_load_lds writes linearly, so the XOR
// swizzle is applied on the GLOBAL source chunk (rule #21): lane l stages
// 16B chunk ((l&7) ^ lrow), giving LDS[r][j] = G[r][j ^ (r&7)]. Fragment
// reads then use short-index ko ^ ((row&7)*8) -> rows 0..7 hit 8 distinct
// banks (2-way across 16 rows = free) instead of 16-way same-bank.
__device__ inline void gload_lds16(const void* g, void* l) {
  __builtin_amdgcn_global_load_lds(
      (const __attribute__((address_space(1))) void*)g,
      (__attribute__((address_space(3))) void*)l, 16, 0, 0);
}

template <int K, bool FUSE>
__global__ __launch_bounds__(256) void gemm_nt(const unsigned short* __restrict__ A,
                                               const unsigned short* __restrict__ Bt,
                                               unsigned short* __restrict__ C,
                                               float* __restrict__ stats,
                                               const float* __restrict__ scsh) {
  __shared__ unsigned short lA[128 * 64];  // [128 m][64 k] (k-chunks swizzled)
  __shared__ unsigned short lB[128 * 64];  // [128 n][64 k]
  __shared__ float sdat[256];              // 128 col sums + 128 col sumsq
  __shared__ float lscsh[FUSE ? 512 : 4];  // BN scale[256] + shift[256]
  int t = threadIdx.x;
  int lane = t & 63, wave = t >> 6;
  int wr = wave >> 1, wc = wave & 1;
  int m0 = blockIdx.x * 128, n0 = blockIdx.y * 128;
  int lrow = lane >> 3;                       // 0..7
  int lcol = (((lane & 7) ^ lrow) << 3);      // swizzled source chunk * 8 shorts
  sdat[t] = 0.f;
  if (FUSE) { lscsh[t] = scsh[t]; lscsh[256 + t] = scsh[256 + t]; }
  f32x4 acc[4][4] = {};
  for (int k0 = 0; k0 < K; k0 += 64) {
#pragma unroll
    for (int i = 0; i < 4; ++i) {
      int row = i * 32 + wave * 8 + lrow;
      gload_lds16(A + (size_t)(m0 + row) * K + k0 + lcol, &lA[i * 2048 + wave * 512]);
    }
#pragma unroll
    for (int i = 0; i < 4; ++i) {
      int row = i * 32 + wave * 8 + lrow;
      gload_lds16(Bt + (size_t)(n0 + row) * K + k0 + lcol, &lB[i * 2048 + wave * 512]);
    }
    __syncthreads();
#pragma unroll
    for (int kk = 0; kk < 2; ++kk) {
      int ko = kk * 32 + (lane >> 4) * 8;
      // BN scale/shift for this lane's 8 channels (FUSE only)
      float scv[8], shv[8];
      if (FUSE) {
        int cb = k0 + ko;
        *(float4*)&scv[0] = *(const float4*)&lscsh[cb];
        *(float4*)&scv[4] = *(const float4*)&lscsh[cb + 4];
        *(float4*)&shv[0] = *(const float4*)&lscsh[256 + cb];
        *(float4*)&shv[4] = *(const float4*)&lscsh[256 + cb + 4];
      }
      bf16x8 af[4], bfr[4];
#pragma unroll
      for (int m = 0; m < 4; ++m) {
        int row = wr * 64 + m * 16 + (lane & 15);
        int kosw = ko ^ ((row & 7) << 3);
        af[m] = *(const bf16x8*)&lA[row * 64 + kosw];
        if (FUSE) {
          union { bf16x8 h; uint32_t w[4]; } u; u.h = af[m];
#pragma unroll
          for (int q = 0; q < 4; ++q) {
            float lo = fmaxf(bflo(u.w[q]) * scv[2 * q] + shv[2 * q], 0.f);
            float hi = fmaxf(bfhi(u.w[q]) * scv[2 * q + 1] + shv[2 * q + 1], 0.f);
            u.w[q] = (uint32_t)f2bf(lo) | ((uint32_t)f2bf(hi) << 16);
          }
          af[m] = u.h;
        }
      }
#pragma unroll
      for (int n2 = 0; n2 < 4; ++n2) {
        int row = wc * 64 + n2 * 16 + (lane & 15);
        int kosw = ko ^ ((row & 7) << 3);
        bfr[n2] = *(const bf16x8*)&lB[row * 64 + kosw];
      }
#pragma unroll
      for (int m = 0; m < 4; ++m)
#pragma unroll
        for (int n2 = 0; n2 < 4; ++n2)
          acc[m][n2] = __builtin_amdgcn_mfma_f32_16x16x32_bf16(af[m], bfr[n2], acc[m][n2], 0, 0, 0);
    }
    __syncthreads();
  }
  // ---- C write (bf16, raw pre-BN values) ----
  int crow0 = m0 + wr * 64 + (lane >> 4) * 4;
  int ccol0 = n0 + wc * 64 + (lane & 15);
#pragma unroll
  for (int m = 0; m < 4; ++m)
#pragma unroll
    for (int n2 = 0; n2 < 4; ++n2) {
      size_t rb = (size_t)(crow0 + m * 16);
      int cc = ccol0 + n2 * 16;
#pragma unroll
      for (int j = 0; j < 4; ++j)
        C[(rb + j) * CO + cc] = f2bf(acc[m][n2][j]);
    }
  // ---- fused BN stats ----
  float s4[4] = {0.f, 0.f, 0.f, 0.f}, q4[4] = {0.f, 0.f, 0.f, 0.f};
#pragma unroll
  for (int m = 0; m < 4; ++m)
#pragma unroll
    for (int n2 = 0; n2 < 4; ++n2)
#pragma unroll
      for (int j = 0; j < 4; ++j) {
        float v = acc[m][n2][j];
        s4[n2] += v;
        q4[n2] += v * v;
      }
#pragma unroll
  for (int n2 = 0; n2 < 4; ++n2) {
    s4[n2] += __shfl_xor(s4[n2], 16);
    q4[n2] += __shfl_xor(q4[n2], 16);
    s4[n2] += __shfl_xor(s4[n2], 32);
    q4[n2] += __shfl_xor(q4[n2], 32);
  }
  if (lane < 16) {
#pragma unroll
    for (int n2 = 0; n2 < 4; ++n2) {
      int cl = wc * 64 + n2 * 16 + lane;
      atomicAdd(&sdat[cl], s4[n2]);
      atomicAdd(&sdat[128 + cl], q4[n2]);
    }
  }
  __syncthreads();
  if (t < 128) {
    atomicAdd(&stats[n0 + t], sdat[t]);
    atomicAdd(&stats[256 + n0 + t], sdat[128 + t]);
  }
}

__global__ void finalize_kernel(const float* __restrict__ stats, const float* __restrict__ g,
                                const float* __restrict__ be, float* __restrict__ scsh) {
  int c = threadIdx.x;
  float mean = stats[c] * (1.f / ROWS);
  float var = stats[256 + c] * (1.f / ROWS) - mean * mean;
  float sc = g[c] * rsqrtf(var + 1e-3f);
  scsh[c] = sc;
  scsh[256 + c] = be[c] - mean * sc;
}

// ----------------------------------------- BN+ReLU apply, fp32 out
__global__ __launch_bounds__(256) void apply_f32(const unsigned short* __restrict__ Y,
                                                 const float* __restrict__ scsh,
                                                 float* __restrict__ out) {
  __shared__ float sc[256], sh[256];
  int t = threadIdx.x;
  sc[t] = scsh[t]; sh[t] = scsh[256 + t];
  __syncthreads();
  size_t base = ((size_t)blockIdx.x * 256 + t) * 8;
  int c0 = (int)(base & 255);
  uint4 v = *(const uint4*)(Y + base);
  uint32_t wv[4] = {v.x, v.y, v.z, v.w};
  float o[8];
#pragma unroll
  for (int q = 0; q < 4; ++q) {
    o[2 * q]     = fmaxf(bflo(wv[q]) * sc[c0 + 2 * q] + sh[c0 + 2 * q], 0.f);
    o[2 * q + 1] = fmaxf(bfhi(wv[q]) * sc[c0 + 2 * q + 1] + sh[c0 + 2 * q + 1], 0.f);
  }
  *(float4*)(out + base) = make_float4(o[0], o[1], o[2], o[3]);
  *(float4*)(out + base + 4) = make_float4(o[4], o[5], o[6], o[7]);
}

extern "C" void kernel_launch(void* const* d_in, const int* in_sizes, int n_in,
                              void* d_out, int out_size, void* d_ws, size_t ws_size,
                              hipStream_t stream) {
  const float* xyz1    = (const float*)d_in[0];
  const float* xyz2    = (const float*)d_in[1];
  const float* points1 = (const float*)d_in[2];
  const float* points2 = (const float*)d_in[3];
  const float* W0      = (const float*)d_in[4];
  const float* g0      = (const float*)d_in[6];
  const float* be0     = (const float*)d_in[7];
  const float* W1      = (const float*)d_in[8];
  const float* g1      = (const float*)d_in[10];
  const float* be1     = (const float*)d_in[11];
  float* out = (float*)d_out;

  // workspace layout (bytes)
  char* ws = (char*)d_ws;
  unsigned short* X   = (unsigned short*)(ws);                       // ROWS*384 bf16 (reused for Y2)
  unsigned short* Y1  = (unsigned short*)(ws + 50331648);            // ROWS*256 bf16
  unsigned short* W0t = (unsigned short*)(ws + 50331648 + 33554432); // 384*256 bf16 (transposed)
  unsigned short* W1t = (unsigned short*)(ws + 50331648 + 33554432 + 196608);
  float* stats = (float*)(ws + 50331648 + 33554432 + 196608 + 131072); // 1024 f32
  float* scsh  = stats + 1024;                                        // 1024 f32
  int*   idx   = (int*)(scsh + 1024);                                 // ROWS*3
  float* wgt   = (float*)(idx + ROWS * 3);                            // ROWS*3
  unsigned short* Y2 = X;  // X buffer free after gemm1

  wt_kernel<<<(CIN * CO + 255) / 256, 256, 0, stream>>>(W0, W0t, CIN, CO, stats);
  wt_kernel<<<(CO * CO + 255) / 256, 256, 0, stream>>>(W1, W1t, CO, CO, stats + 512);

  nn_kernel<<<BB * (NN / 32), 256, 0, stream>>>(xyz1, xyz2, idx, wgt);
  interp_kernel<<<ROWS / 2, 256, 0, stream>>>(points2, points1, idx, wgt, X);

  dim3 gg(ROWS / 128, 2);
  gemm_nt<CIN, false><<<gg, 256, 0, stream>>>(X, W0t, Y1, stats, nullptr);
  finalize_kernel<<<1, 256, 0, stream>>>(stats, g0, be0, scsh);

  gemm_nt<CO, true><<<gg, 256, 0, stream>>>(Y1, W1t, Y2, stats + 512, scsh);
  finalize_kernel<<<1, 256, 0, stream>>>(stats + 512, g1, be1, scsh + 512);

  apply_f32<<<(size_t)ROWS * CO / (256 * 8), 256, 0, stream>>>(Y2, scsh + 512, out);
}

// Round 6
// 180.627 us; speedup vs baseline: 1.0458x; 1.0458x over previous
//
#include <hip/hip_runtime.h>
#include <hip/hip_bf16.h>
#include <stdint.h>

#define BB 16
#define NN 4096
#define MM 1024
#define C1 128
#define C2 256
#define CIN 384
#define CO 256
#define ROWS (BB * NN)

typedef __attribute__((ext_vector_type(8))) short bf16x8;
typedef __attribute__((ext_vector_type(4))) float f32x4;

__device__ inline float u2f(uint32_t u) { union { uint32_t u; float f; } v; v.u = u; return v.f; }
__device__ inline uint32_t f2u(float f) { union { float f; uint32_t u; } v; v.f = f; return v.u; }
// round-to-nearest-even f32 -> bf16
__device__ inline unsigned short f2bf(float f) {
  uint32_t u = f2u(f);
  uint32_t r = u + 0x7fffu + ((u >> 16) & 1u);
  return (unsigned short)(r >> 16);
}
__device__ inline float bflo(uint32_t w) { return u2f(w << 16); }
__device__ inline float bfhi(uint32_t w) { return u2f(w & 0xffff0000u); }

// ---------------------------------------------------------------- three_nn
#define NN_INS(dd, jj_)                                        \
  {                                                            \
    bool c0 = (dd) < e0, c1 = (dd) < e1, c2 = (dd) < e2;       \
    e2 = c2 ? (c1 ? e1 : (dd)) : e2;                           \
    i2 = c2 ? (c1 ? i1 : (jj_)) : i2;                          \
    e1 = c1 ? (c0 ? e0 : (dd)) : e1;                           \
    i1 = c1 ? (c0 ? i0 : (jj_)) : i1;                          \
    e0 = c0 ? (dd) : e0;                                       \
    i0 = c0 ? (jj_) : i0;                                      \
  }

__global__ __launch_bounds__(256) void nn_kernel(const float* __restrict__ xyz1,
                                                 const float* __restrict__ xyz2,
                                                 int* __restrict__ idx,
                                                 float* __restrict__ wgt) {
  __shared__ float4 q[MM];  // 16 KB
  int b = blockIdx.x >> 7;                 // 128 blocks per batch (N/32)
  int qbase = (blockIdx.x & 127) << 5;     // 32 queries per block
  const float* x2 = xyz2 + (size_t)b * MM * 3;
  for (int j = threadIdx.x; j < MM; j += 256)
    q[j] = make_float4(x2[j * 3 + 0], x2[j * 3 + 1], x2[j * 3 + 2], 0.f);
  __syncthreads();
  int n = qbase + (threadIdx.x >> 3);
  int tq = threadIdx.x & 7;
  const float* p = xyz1 + ((size_t)b * NN + n) * 3;
  float px = p[0], py = p[1], pz = p[2];
  float e0 = 1e30f, e1 = 1e30f, e2 = 1e30f;
  int i0 = 0, i1 = 0, i2 = 0;
#pragma unroll 8
  for (int jj = 0; jj < MM / 8; ++jj) {
    int j = jj * 8 + tq;
    float4 qv = q[j];
    float dx = px - qv.x, dy = py - qv.y, dz = pz - qv.z;
    float d = dx * dx + dy * dy + dz * dz;
    NN_INS(d, j);
  }
#pragma unroll
  for (int mk = 1; mk <= 4; mk <<= 1) {
    float f0 = __shfl_xor(e0, mk), f1 = __shfl_xor(e1, mk), f2 = __shfl_xor(e2, mk);
    int j0 = __shfl_xor(i0, mk), j1 = __shfl_xor(i1, mk), j2 = __shfl_xor(i2, mk);
    NN_INS(f0, j0);
    NN_INS(f1, j1);
    NN_INS(f2, j2);
  }
  if (tq == 0) {
    float a0 = fmaxf(e0, 1e-10f), a1 = fmaxf(e1, 1e-10f), a2 = fmaxf(e2, 1e-10f);
    float v0 = 1.f / a0, v1 = 1.f / a1, v2 = 1.f / a2;
    float inv = 1.f / (v0 + v1 + v2);
    size_t base = ((size_t)b * NN + n) * 3;
    idx[base + 0] = i0; idx[base + 1] = i1; idx[base + 2] = i2;
    wgt[base + 0] = v0 * inv; wgt[base + 1] = v1 * inv; wgt[base + 2] = v2 * inv;
  }
}

// -------------------------------------------- interpolate + concat -> x bf16
__global__ __launch_bounds__(256) void interp_kernel(const float* __restrict__ points2,
                                                     const float* __restrict__ points1,
                                                     const int* __restrict__ idx,
                                                     const float* __restrict__ wgt,
                                                     unsigned short* __restrict__ X) {
  int row = blockIdx.x * 2 + (threadIdx.x >> 7);
  int t = threadIdx.x & 127;
  int b = row >> 12;  // N = 4096 rows per batch
  unsigned short* xr = X + (size_t)row * CIN;
  if (t < 64) {
    const int* id = idx + (size_t)row * 3;
    const float* w = wgt + (size_t)row * 3;
    const float* p2 = points2 + (size_t)b * MM * C2 + t * 4;
    float w0 = w[0], w1 = w[1], w2 = w[2];
    float4 a0 = *(const float4*)(p2 + (size_t)id[0] * C2);
    float4 a1 = *(const float4*)(p2 + (size_t)id[1] * C2);
    float4 a2 = *(const float4*)(p2 + (size_t)id[2] * C2);
    ushort4 o;
    o.x = f2bf(w0 * a0.x + w1 * a1.x + w2 * a2.x);
    o.y = f2bf(w0 * a0.y + w1 * a1.y + w2 * a2.y);
    o.z = f2bf(w0 * a0.z + w1 * a1.z + w2 * a2.z);
    o.w = f2bf(w0 * a0.w + w1 * a1.w + w2 * a2.w);
    *(ushort4*)(xr + t * 4) = o;
  } else if (t < 96) {
    int c = (t - 64) * 4;
    float4 a = *(const float4*)(points1 + (size_t)row * C1 + c);
    ushort4 o;
    o.x = f2bf(a.x); o.y = f2bf(a.y); o.z = f2bf(a.z); o.w = f2bf(a.w);
    *(ushort4*)(xr + C2 + c) = o;
  }
}

// ---------------- both weight transposes + stats zeroing in ONE launch
// blocks 0..383: W0t (384*256 elems); blocks 384..639: W1t (n = bid-384).
__global__ __launch_bounds__(256) void wt_both(const float* __restrict__ W0,
                                               const float* __restrict__ W1,
                                               unsigned short* __restrict__ W0t,
                                               unsigned short* __restrict__ W1t,
                                               float* __restrict__ stats) {
  int t = threadIdx.x, bid = blockIdx.x;
  if (bid == 0) { stats[t] = 0.f; stats[256 + t] = 0.f; }
  if (bid == 1) { stats[512 + t] = 0.f; stats[768 + t] = 0.f; }
  if (bid < 384) {
    int i = bid * 256 + t;          // W0t index: [n][k], n = i/384, k = i%384
    int n = i / CIN, k = i - n * CIN;
    W0t[i] = f2bf(W0[(size_t)k * CO + n]);
  } else {
    int n = bid - 384;              // W1t[n][k], k = t
    W1t[n * CO + t] = f2bf(W1[(size_t)t * CO + n]);
  }
}

// ---------------------------------------------------------------- bf16 GEMM
// C[m][n] = sum_k A'[m][k] * Bt[n][k];  A' = FUSE ? relu(A*sc+sh) : A.
// T3 minimum-2-phase: LDS double-buffer, next tile's global_load_lds issued
// BEFORE current tile's compute, ONE __syncthreads per K-step (its implicit
// vmcnt(0) drain finds loads that aged under the whole compute phase).
// T2 source-side XOR swizzle kept (conflicts stay 0, costs nothing).
// FUSE folds the PREVIOUS layer's BN scale/shift computation into the
// prologue (reads raw stats + gamma/beta; every block recomputes - trivial).
__device__ inline void gload_lds16(const void* g, void* l) {
  __builtin_amdgcn_global_load_lds(
      (const __attribute__((address_space(1))) void*)g,
      (__attribute__((address_space(3))) void*)l, 16, 0, 0);
}

template <int K, bool FUSE>
__global__ __launch_bounds__(256) void gemm_nt(const unsigned short* __restrict__ A,
                                               const unsigned short* __restrict__ Bt,
                                               unsigned short* __restrict__ C,
                                               float* __restrict__ stats,
                                               const float* __restrict__ statsPrev,
                                               const float* __restrict__ g,
                                               const float* __restrict__ be) {
  constexpr int NT = K / 64;
  __shared__ unsigned short lA[2][128 * 64];  // [buf][128 m][64 k] swizzled
  __shared__ unsigned short lB[2][128 * 64];
  __shared__ float sdat[256];                 // 128 col sums + 128 col sumsq
  __shared__ float lscsh[FUSE ? 512 : 4];     // BN scale[256] + shift[256]
  int t = threadIdx.x;
  int lane = t & 63, wave = t >> 6;
  int wr = wave >> 1, wc = wave & 1;
  int m0 = blockIdx.x * 128, n0 = blockIdx.y * 128;
  int lrow = lane >> 3;                       // 0..7
  int lcol = (((lane & 7) ^ lrow) << 3);      // swizzled source chunk * 8

#define STAGE(buf, k0)                                                         \
  {                                                                            \
    _Pragma("unroll") for (int i = 0; i < 4; ++i) {                            \
      int row = i * 32 + wave * 8 + lrow;                                      \
      gload_lds16(A + (size_t)(m0 + row) * K + (k0) + lcol,                    \
                  &lA[buf][i * 2048 + wave * 512]);                            \
    }                                                                          \
    _Pragma("unroll") for (int i = 0; i < 4; ++i) {                            \
      int row = i * 32 + wave * 8 + lrow;                                      \
      gload_lds16(Bt + (size_t)(n0 + row) * K + (k0) + lcol,                   \
                  &lB[buf][i * 2048 + wave * 512]);                            \
    }                                                                          \
  }

  // prologue: stage tile 0, init sdat + BN scale/shift
  STAGE(0, 0);
  sdat[t] = 0.f;
  if (FUSE) {
    float mean = statsPrev[t] * (1.f / ROWS);
    float var = statsPrev[256 + t] * (1.f / ROWS) - mean * mean;
    float sc = g[t] * rsqrtf(var + 1e-3f);
    lscsh[t] = sc;
    lscsh[256 + t] = be[t] - mean * sc;
  }
  __syncthreads();

  f32x4 acc[4][4] = {};

#define COMPUTE(buf, k0)                                                       \
  {                                                                            \
    _Pragma("unroll") for (int kk = 0; kk < 2; ++kk) {                         \
      int ko = kk * 32 + (lane >> 4) * 8;                                      \
      float scv[8], shv[8];                                                    \
      if (FUSE) {                                                              \
        int cb = (k0) + ko;                                                    \
        *(float4*)&scv[0] = *(const float4*)&lscsh[cb];                        \
        *(float4*)&scv[4] = *(const float4*)&lscsh[cb + 4];                    \
        *(float4*)&shv[0] = *(const float4*)&lscsh[256 + cb];                  \
        *(float4*)&shv[4] = *(const float4*)&lscsh[256 + cb + 4];              \
      }                                                                        \
      bf16x8 af[4], bfr[4];                                                    \
      _Pragma("unroll") for (int m = 0; m < 4; ++m) {                          \
        int row = wr * 64 + m * 16 + (lane & 15);                              \
        int kosw = ko ^ ((row & 7) << 3);                                      \
        af[m] = *(const bf16x8*)&lA[buf][row * 64 + kosw];                     \
        if (FUSE) {                                                            \
          union { bf16x8 h; uint32_t w[4]; } u; u.h = af[m];                   \
          _Pragma("unroll") for (int q = 0; q < 4; ++q) {                      \
            float lo = fmaxf(bflo(u.w[q]) * scv[2 * q] + shv[2 * q], 0.f);     \
            float hi = fmaxf(bfhi(u.w[q]) * scv[2 * q + 1] + shv[2 * q + 1], 0.f); \
            u.w[q] = (uint32_t)f2bf(lo) | ((uint32_t)f2bf(hi) << 16);          \
          }                                                                    \
          af[m] = u.h;                                                         \
        }                                                                      \
      }                                                                        \
      _Pragma("unroll") for (int n2 = 0; n2 < 4; ++n2) {                       \
        int row = wc * 64 + n2 * 16 + (lane & 15);                             \
        int kosw = ko ^ ((row & 7) << 3);                                      \
        bfr[n2] = *(const bf16x8*)&lB[buf][row * 64 + kosw];                   \
      }                                                                        \
      _Pragma("unroll") for (int m = 0; m < 4; ++m)                            \
        _Pragma("unroll") for (int n2 = 0; n2 < 4; ++n2)                       \
          acc[m][n2] = __builtin_amdgcn_mfma_f32_16x16x32_bf16(af[m], bfr[n2], acc[m][n2], 0, 0, 0); \
    }                                                                          \
  }

#pragma unroll
  for (int tt = 0; tt < NT - 1; ++tt) {
    STAGE((tt + 1) & 1, (tt + 1) * 64);   // issue next tile early
    COMPUTE(tt & 1, tt * 64);             // compute current tile
    __syncthreads();                      // drain next-tile loads + sync reads
  }
  COMPUTE((NT - 1) & 1, (NT - 1) * 64);
#undef STAGE
#undef COMPUTE

  // ---- C write (bf16, raw pre-BN values) ----
  int crow0 = m0 + wr * 64 + (lane >> 4) * 4;
  int ccol0 = n0 + wc * 64 + (lane & 15);
#pragma unroll
  for (int m = 0; m < 4; ++m)
#pragma unroll
    for (int n2 = 0; n2 < 4; ++n2) {
      size_t rb = (size_t)(crow0 + m * 16);
      int cc = ccol0 + n2 * 16;
#pragma unroll
      for (int j = 0; j < 4; ++j)
        C[(rb + j) * CO + cc] = f2bf(acc[m][n2][j]);
    }
  // ---- fused BN stats ----
  float s4[4] = {0.f, 0.f, 0.f, 0.f}, q4[4] = {0.f, 0.f, 0.f, 0.f};
#pragma unroll
  for (int m = 0; m < 4; ++m)
#pragma unroll
    for (int n2 = 0; n2 < 4; ++n2)
#pragma unroll
      for (int j = 0; j < 4; ++j) {
        float v = acc[m][n2][j];
        s4[n2] += v;
        q4[n2] += v * v;
      }
#pragma unroll
  for (int n2 = 0; n2 < 4; ++n2) {
    s4[n2] += __shfl_xor(s4[n2], 16);
    q4[n2] += __shfl_xor(q4[n2], 16);
    s4[n2] += __shfl_xor(s4[n2], 32);
    q4[n2] += __shfl_xor(q4[n2], 32);
  }
  if (lane < 16) {
#pragma unroll
    for (int n2 = 0; n2 < 4; ++n2) {
      int cl = wc * 64 + n2 * 16 + lane;
      atomicAdd(&sdat[cl], s4[n2]);
      atomicAdd(&sdat[128 + cl], q4[n2]);
    }
  }
  __syncthreads();
  if (t < 128) {
    atomicAdd(&stats[n0 + t], sdat[t]);
    atomicAdd(&stats[256 + n0 + t], sdat[128 + t]);
  }
}

// ------------------- BN+ReLU apply, fp32 out (finalize folded into prologue)
__global__ __launch_bounds__(256) void apply_f32(const unsigned short* __restrict__ Y,
                                                 const float* __restrict__ stats2,
                                                 const float* __restrict__ g,
                                                 const float* __restrict__ be,
                                                 float* __restrict__ out) {
  __shared__ float sc[256], sh[256];
  int t = threadIdx.x;
  {
    float mean = stats2[t] * (1.f / ROWS);
    float var = stats2[256 + t] * (1.f / ROWS) - mean * mean;
    float s = g[t] * rsqrtf(var + 1e-3f);
    sc[t] = s;
    sh[t] = be[t] - mean * s;
  }
  __syncthreads();
  size_t base = ((size_t)blockIdx.x * 256 + t) * 8;
  int c0 = (int)(base & 255);
  uint4 v = *(const uint4*)(Y + base);
  uint32_t wv[4] = {v.x, v.y, v.z, v.w};
  float o[8];
#pragma unroll
  for (int q = 0; q < 4; ++q) {
    o[2 * q]     = fmaxf(bflo(wv[q]) * sc[c0 + 2 * q] + sh[c0 + 2 * q], 0.f);
    o[2 * q + 1] = fmaxf(bfhi(wv[q]) * sc[c0 + 2 * q + 1] + sh[c0 + 2 * q + 1], 0.f);
  }
  *(float4*)(out + base) = make_float4(o[0], o[1], o[2], o[3]);
  *(float4*)(out + base + 4) = make_float4(o[4], o[5], o[6], o[7]);
}

extern "C" void kernel_launch(void* const* d_in, const int* in_sizes, int n_in,
                              void* d_out, int out_size, void* d_ws, size_t ws_size,
                              hipStream_t stream) {
  const float* xyz1    = (const float*)d_in[0];
  const float* xyz2    = (const float*)d_in[1];
  const float* points1 = (const float*)d_in[2];
  const float* points2 = (const float*)d_in[3];
  const float* W0      = (const float*)d_in[4];
  const float* g0      = (const float*)d_in[6];
  const float* be0     = (const float*)d_in[7];
  const float* W1      = (const float*)d_in[8];
  const float* g1      = (const float*)d_in[10];
  const float* be1     = (const float*)d_in[11];
  float* out = (float*)d_out;

  // workspace layout (bytes)
  char* ws = (char*)d_ws;
  unsigned short* X   = (unsigned short*)(ws);                       // ROWS*384 bf16 (reused for Y2)
  unsigned short* Y1  = (unsigned short*)(ws + 50331648);            // ROWS*256 bf16
  unsigned short* W0t = (unsigned short*)(ws + 50331648 + 33554432); // 384*256 bf16 (transposed)
  unsigned short* W1t = (unsigned short*)(ws + 50331648 + 33554432 + 196608);
  float* stats = (float*)(ws + 50331648 + 33554432 + 196608 + 131072); // 1024 f32
  int*   idx   = (int*)(stats + 1024);                                 // ROWS*3
  float* wgt   = (float*)(idx + ROWS * 3);                             // ROWS*3
  unsigned short* Y2 = X;  // X buffer free after gemm1

  wt_both<<<640, 256, 0, stream>>>(W0, W1, W0t, W1t, stats);
  nn_kernel<<<BB * (NN / 32), 256, 0, stream>>>(xyz1, xyz2, idx, wgt);
  interp_kernel<<<ROWS / 2, 256, 0, stream>>>(points2, points1, idx, wgt, X);

  dim3 gg(ROWS / 128, 2);
  gemm_nt<CIN, false><<<gg, 256, 0, stream>>>(X, W0t, Y1, stats, nullptr, nullptr, nullptr);
  gemm_nt<CO, true><<<gg, 256, 0, stream>>>(Y1, W1t, Y2, stats + 512, stats, g0, be0);
  apply_f32<<<(size_t)ROWS * CO / (256 * 8), 256, 0, stream>>>(Y2, stats + 512, g1, be1, out);
}

// Round 7
// 160.388 us; speedup vs baseline: 1.1777x; 1.1262x over previous
//
#include <hip/hip_runtime.h>
#include <hip/hip_bf16.h>
#include <stdint.h>

#define BB 16
#define NN 4096
#define MM 1024
#define C1 128
#define C2 256
#define CIN 384
#define CO 256
#define ROWS (BB * NN)

typedef __attribute__((ext_vector_type(8))) short bf16x8;
typedef __attribute__((ext_vector_type(4))) float f32x4;

__device__ inline float u2f(uint32_t u) { union { uint32_t u; float f; } v; v.u = u; return v.f; }
__device__ inline uint32_t f2u(float f) { union { float f; uint32_t u; } v; v.f = f; return v.u; }
// round-to-nearest-even f32 -> bf16
__device__ inline unsigned short f2bf(float f) {
  uint32_t u = f2u(f);
  uint32_t r = u + 0x7fffu + ((u >> 16) & 1u);
  return (unsigned short)(r >> 16);
}
__device__ inline float bflo(uint32_t w) { return u2f(w << 16); }
__device__ inline float bfhi(uint32_t w) { return u2f(w & 0xffff0000u); }
// packed RNE f32x2 -> bf16x2 (compiler emits v_cvt_pk_bf16_f32)
__device__ inline uint32_t pk2bf(float lo, float hi) {
  union { __hip_bfloat162 h; uint32_t u; } c;
  c.h = __float22bfloat162_rn(make_float2(lo, hi));
  return c.u;
}

// ---------------------------------------------------------------- three_nn
#define NN_INS(dd, jj_)                                        \
  {                                                            \
    bool c0 = (dd) < e0, c1 = (dd) < e1, c2 = (dd) < e2;       \
    e2 = c2 ? (c1 ? e1 : (dd)) : e2;                           \
    i2 = c2 ? (c1 ? i1 : (jj_)) : i2;                          \
    e1 = c1 ? (c0 ? e0 : (dd)) : e1;                           \
    i1 = c1 ? (c0 ? i0 : (jj_)) : i1;                          \
    e0 = c0 ? (dd) : e0;                                       \
    i0 = c0 ? (jj_) : i0;                                      \
  }

__global__ __launch_bounds__(256) void nn_kernel(const float* __restrict__ xyz1,
                                                 const float* __restrict__ xyz2,
                                                 int* __restrict__ idx,
                                                 float* __restrict__ wgt) {
  __shared__ float4 q[MM];  // 16 KB
  int b = blockIdx.x >> 7;                 // 128 blocks per batch (N/32)
  int qbase = (blockIdx.x & 127) << 5;     // 32 queries per block
  const float* x2 = xyz2 + (size_t)b * MM * 3;
  for (int j = threadIdx.x; j < MM; j += 256)
    q[j] = make_float4(x2[j * 3 + 0], x2[j * 3 + 1], x2[j * 3 + 2], 0.f);
  __syncthreads();
  int n = qbase + (threadIdx.x >> 3);
  int tq = threadIdx.x & 7;
  const float* p = xyz1 + ((size_t)b * NN + n) * 3;
  float px = p[0], py = p[1], pz = p[2];
  float e0 = 1e30f, e1 = 1e30f, e2 = 1e30f;
  int i0 = 0, i1 = 0, i2 = 0;
#pragma unroll 8
  for (int jj = 0; jj < MM / 8; ++jj) {
    int j = jj * 8 + tq;
    float4 qv = q[j];
    float dx = px - qv.x, dy = py - qv.y, dz = pz - qv.z;
    float d = dx * dx + dy * dy + dz * dz;
    NN_INS(d, j);
  }
#pragma unroll
  for (int mk = 1; mk <= 4; mk <<= 1) {
    float f0 = __shfl_xor(e0, mk), f1 = __shfl_xor(e1, mk), f2 = __shfl_xor(e2, mk);
    int j0 = __shfl_xor(i0, mk), j1 = __shfl_xor(i1, mk), j2 = __shfl_xor(i2, mk);
    NN_INS(f0, j0);
    NN_INS(f1, j1);
    NN_INS(f2, j2);
  }
  if (tq == 0) {
    float a0 = fmaxf(e0, 1e-10f), a1 = fmaxf(e1, 1e-10f), a2 = fmaxf(e2, 1e-10f);
    float v0 = 1.f / a0, v1 = 1.f / a1, v2 = 1.f / a2;
    float inv = 1.f / (v0 + v1 + v2);
    size_t base = ((size_t)b * NN + n) * 3;
    idx[base + 0] = i0; idx[base + 1] = i1; idx[base + 2] = i2;
    wgt[base + 0] = v0 * inv; wgt[base + 1] = v1 * inv; wgt[base + 2] = v2 * inv;
  }
}

// -------------------------------------------- interpolate + concat -> x bf16
__global__ __launch_bounds__(256) void interp_kernel(const float* __restrict__ points2,
                                                     const float* __restrict__ points1,
                                                     const int* __restrict__ idx,
                                                     const float* __restrict__ wgt,
                                                     unsigned short* __restrict__ X) {
  int row = blockIdx.x * 2 + (threadIdx.x >> 7);
  int t = threadIdx.x & 127;
  int b = row >> 12;  // N = 4096 rows per batch
  unsigned short* xr = X + (size_t)row * CIN;
  if (t < 64) {
    const int* id = idx + (size_t)row * 3;
    const float* w = wgt + (size_t)row * 3;
    const float* p2 = points2 + (size_t)b * MM * C2 + t * 4;
    float w0 = w[0], w1 = w[1], w2 = w[2];
    float4 a0 = *(const float4*)(p2 + (size_t)id[0] * C2);
    float4 a1 = *(const float4*)(p2 + (size_t)id[1] * C2);
    float4 a2 = *(const float4*)(p2 + (size_t)id[2] * C2);
    ushort4 o;
    o.x = f2bf(w0 * a0.x + w1 * a1.x + w2 * a2.x);
    o.y = f2bf(w0 * a0.y + w1 * a1.y + w2 * a2.y);
    o.z = f2bf(w0 * a0.z + w1 * a1.z + w2 * a2.z);
    o.w = f2bf(w0 * a0.w + w1 * a1.w + w2 * a2.w);
    *(ushort4*)(xr + t * 4) = o;
  } else if (t < 96) {
    int c = (t - 64) * 4;
    float4 a = *(const float4*)(points1 + (size_t)row * C1 + c);
    ushort4 o;
    o.x = f2bf(a.x); o.y = f2bf(a.y); o.z = f2bf(a.z); o.w = f2bf(a.w);
    *(ushort4*)(xr + C2 + c) = o;
  }
}

// ---------------- both weight transposes + stats zeroing in ONE launch
__global__ __launch_bounds__(256) void wt_both(const float* __restrict__ W0,
                                               const float* __restrict__ W1,
                                               unsigned short* __restrict__ W0t,
                                               unsigned short* __restrict__ W1t,
                                               float* __restrict__ stats) {
  int t = threadIdx.x, bid = blockIdx.x;
  if (bid == 0) { stats[t] = 0.f; stats[256 + t] = 0.f; }
  if (bid == 1) { stats[512 + t] = 0.f; stats[768 + t] = 0.f; }
  if (bid < 384) {
    int i = bid * 256 + t;          // W0t index: [n][k], n = i/384, k = i%384
    int n = i / CIN, k = i - n * CIN;
    W0t[i] = f2bf(W0[(size_t)k * CO + n]);
  } else {
    int n = bid - 384;              // W1t[n][k], k = t
    W1t[n * CO + t] = f2bf(W1[(size_t)t * CO + n]);
  }
}

// ---------------------------------------------------------------- bf16 GEMM
// C[m][n] = sum_k A'[m][k] * Bt[n][k];  A' = FUSE ? relu(A*sc+sh) : A.
// Single-buffer 2-phase, 3 blocks/CU (TLP absorbs loaded-memory latency):
// __launch_bounds__(256,3) caps arch VGPR ~106 (+64 acc AGPR = 170 budget).
// T2 source-side XOR swizzle kept (LDS conflicts = 0, free).
// Pair-XCD swizzle: the two 128-col panels of one row-slab get blockIdx.x
// values congruent mod 8 -> same XCD -> the A-slab re-read is an L2 hit.
__device__ inline void gload_lds16(const void* g, void* l) {
  __builtin_amdgcn_global_load_lds(
      (const __attribute__((address_space(1))) void*)g,
      (__attribute__((address_space(3))) void*)l, 16, 0, 0);
}

template <int K, bool FUSE>
__global__ __launch_bounds__(256, 3) void gemm_nt(const unsigned short* __restrict__ A,
                                                  const unsigned short* __restrict__ Bt,
                                                  unsigned short* __restrict__ C,
                                                  float* __restrict__ stats,
                                                  const float* __restrict__ statsPrev,
                                                  const float* __restrict__ g,
                                                  const float* __restrict__ be) {
  constexpr int NT = K / 64;
  __shared__ unsigned short lA[128 * 64];  // [128 m][64 k] (chunks swizzled)
  __shared__ unsigned short lB[128 * 64];
  __shared__ float sdat[256];              // 128 col sums + 128 col sumsq
  __shared__ float lscsh[FUSE ? 512 : 4];  // BN scale[256] + shift[256]
  int t = threadIdx.x;
  int lane = t & 63, wave = t >> 6;
  int wr = wave >> 1, wc = wave & 1;
  // pair-XCD swizzle: tile ti (0..511), panel q (0..1); bids ti*? arranged so
  // (ti,0) and (ti,1) differ by 8 -> same XCD under bid%8 round-robin.
  int gb = blockIdx.x >> 4, rb = blockIdx.x & 15;
  int q = rb >> 3, ti = (gb << 3) + (rb & 7);
  int m0 = ti * 128, n0 = q * 128;
  int lrow = lane >> 3;                       // 0..7
  int lcol = (((lane & 7) ^ lrow) << 3);      // swizzled source chunk * 8

#define STAGE(k0)                                                              \
  {                                                                            \
    _Pragma("unroll") for (int i = 0; i < 4; ++i) {                            \
      int row = i * 32 + wave * 8 + lrow;                                      \
      gload_lds16(A + (size_t)(m0 + row) * K + (k0) + lcol,                    \
                  &lA[i * 2048 + wave * 512]);                                 \
    }                                                                          \
    _Pragma("unroll") for (int i = 0; i < 4; ++i) {                            \
      int row = i * 32 + wave * 8 + lrow;                                      \
      gload_lds16(Bt + (size_t)(n0 + row) * K + (k0) + lcol,                   \
                  &lB[i * 2048 + wave * 512]);                                 \
    }                                                                          \
  }

  sdat[t] = 0.f;
  if (FUSE) {
    float mean = statsPrev[t] * (1.f / ROWS);
    float var = statsPrev[256 + t] * (1.f / ROWS) - mean * mean;
    float sc = g[t] * rsqrtf(var + 1e-3f);
    lscsh[t] = sc;
    lscsh[256 + t] = be[t] - mean * sc;
  }

  f32x4 acc[4][4] = {};

#define COMPUTE(k0)                                                            \
  {                                                                            \
    _Pragma("unroll") for (int kk = 0; kk < 2; ++kk) {                         \
      int ko = kk * 32 + (lane >> 4) * 8;                                      \
      float scv[8], shv[8];                                                    \
      if (FUSE) {                                                              \
        int cb = (k0) + ko;                                                    \
        *(float4*)&scv[0] = *(const float4*)&lscsh[cb];                        \
        *(float4*)&scv[4] = *(const float4*)&lscsh[cb + 4];                    \
        *(float4*)&shv[0] = *(const float4*)&lscsh[256 + cb];                  \
        *(float4*)&shv[4] = *(const float4*)&lscsh[256 + cb + 4];              \
      }                                                                        \
      bf16x8 af[4], bfr[4];                                                    \
      _Pragma("unroll") for (int m = 0; m < 4; ++m) {                          \
        int row = wr * 64 + m * 16 + (lane & 15);                              \
        int kosw = ko ^ ((row & 7) << 3);                                      \
        af[m] = *(const bf16x8*)&lA[row * 64 + kosw];                          \
        if (FUSE) {                                                            \
          union { bf16x8 h; uint32_t w[4]; } u; u.h = af[m];                   \
          _Pragma("unroll") for (int q_ = 0; q_ < 4; ++q_) {                   \
            float lo = fmaxf(bflo(u.w[q_]) * scv[2 * q_] + shv[2 * q_], 0.f);  \
            float hi = fmaxf(bfhi(u.w[q_]) * scv[2 * q_ + 1] + shv[2 * q_ + 1], 0.f); \
            u.w[q_] = pk2bf(lo, hi);                                           \
          }                                                                    \
          af[m] = u.h;                                                         \
        }                                                                      \
      }                                                                        \
      _Pragma("unroll") for (int n2 = 0; n2 < 4; ++n2) {                       \
        int row = wc * 64 + n2 * 16 + (lane & 15);                             \
        int kosw = ko ^ ((row & 7) << 3);                                      \
        bfr[n2] = *(const bf16x8*)&lB[row * 64 + kosw];                        \
      }                                                                        \
      _Pragma("unroll") for (int m = 0; m < 4; ++m)                            \
        _Pragma("unroll") for (int n2 = 0; n2 < 4; ++n2)                       \
          acc[m][n2] = __builtin_amdgcn_mfma_f32_16x16x32_bf16(af[m], bfr[n2], acc[m][n2], 0, 0, 0); \
    }                                                                          \
  }

#pragma unroll
  for (int tt = 0; tt < NT; ++tt) {
    STAGE(tt * 64);
    __syncthreads();       // drain staging (vmcnt) + publish LDS
    COMPUTE(tt * 64);
    __syncthreads();       // protect buffer before next-tile overwrite
  }
#undef STAGE
#undef COMPUTE

  // ---- C write (bf16, raw pre-BN values) ----
  int crow0 = m0 + wr * 64 + (lane >> 4) * 4;
  int ccol0 = n0 + wc * 64 + (lane & 15);
#pragma unroll
  for (int m = 0; m < 4; ++m)
#pragma unroll
    for (int n2 = 0; n2 < 4; ++n2) {
      size_t rb2 = (size_t)(crow0 + m * 16);
      int cc = ccol0 + n2 * 16;
#pragma unroll
      for (int j = 0; j < 4; ++j)
        C[(rb2 + j) * CO + cc] = f2bf(acc[m][n2][j]);
    }
  // ---- fused BN stats ----
  float s4[4] = {0.f, 0.f, 0.f, 0.f}, q4[4] = {0.f, 0.f, 0.f, 0.f};
#pragma unroll
  for (int m = 0; m < 4; ++m)
#pragma unroll
    for (int n2 = 0; n2 < 4; ++n2)
#pragma unroll
      for (int j = 0; j < 4; ++j) {
        float v = acc[m][n2][j];
        s4[n2] += v;
        q4[n2] += v * v;
      }
#pragma unroll
  for (int n2 = 0; n2 < 4; ++n2) {
    s4[n2] += __shfl_xor(s4[n2], 16);
    q4[n2] += __shfl_xor(q4[n2], 16);
    s4[n2] += __shfl_xor(s4[n2], 32);
    q4[n2] += __shfl_xor(q4[n2], 32);
  }
  if (lane < 16) {
#pragma unroll
    for (int n2 = 0; n2 < 4; ++n2) {
      int cl = wc * 64 + n2 * 16 + lane;
      atomicAdd(&sdat[cl], s4[n2]);
      atomicAdd(&sdat[128 + cl], q4[n2]);
    }
  }
  __syncthreads();
  if (t < 128) {
    atomicAdd(&stats[n0 + t], sdat[t]);
    atomicAdd(&stats[256 + n0 + t], sdat[128 + t]);
  }
}

// ------------------- BN+ReLU apply, fp32 out (finalize folded into prologue)
__global__ __launch_bounds__(256) void apply_f32(const unsigned short* __restrict__ Y,
                                                 const float* __restrict__ stats2,
                                                 const float* __restrict__ g,
                                                 const float* __restrict__ be,
                                                 float* __restrict__ out) {
  __shared__ float sc[256], sh[256];
  int t = threadIdx.x;
  {
    float mean = stats2[t] * (1.f / ROWS);
    float var = stats2[256 + t] * (1.f / ROWS) - mean * mean;
    float s = g[t] * rsqrtf(var + 1e-3f);
    sc[t] = s;
    sh[t] = be[t] - mean * s;
  }
  __syncthreads();
  size_t base = ((size_t)blockIdx.x * 256 + t) * 8;
  int c0 = (int)(base & 255);
  uint4 v = *(const uint4*)(Y + base);
  uint32_t wv[4] = {v.x, v.y, v.z, v.w};
  float o[8];
#pragma unroll
  for (int q = 0; q < 4; ++q) {
    o[2 * q]     = fmaxf(bflo(wv[q]) * sc[c0 + 2 * q] + sh[c0 + 2 * q], 0.f);
    o[2 * q + 1] = fmaxf(bfhi(wv[q]) * sc[c0 + 2 * q + 1] + sh[c0 + 2 * q + 1], 0.f);
  }
  *(float4*)(out + base) = make_float4(o[0], o[1], o[2], o[3]);
  *(float4*)(out + base + 4) = make_float4(o[4], o[5], o[6], o[7]);
}

extern "C" void kernel_launch(void* const* d_in, const int* in_sizes, int n_in,
                              void* d_out, int out_size, void* d_ws, size_t ws_size,
                              hipStream_t stream) {
  const float* xyz1    = (const float*)d_in[0];
  const float* xyz2    = (const float*)d_in[1];
  const float* points1 = (const float*)d_in[2];
  const float* points2 = (const float*)d_in[3];
  const float* W0      = (const float*)d_in[4];
  const float* g0      = (const float*)d_in[6];
  const float* be0     = (const float*)d_in[7];
  const float* W1      = (const float*)d_in[8];
  const float* g1      = (const float*)d_in[10];
  const float* be1     = (const float*)d_in[11];
  float* out = (float*)d_out;

  // workspace layout (bytes)
  char* ws = (char*)d_ws;
  unsigned short* X   = (unsigned short*)(ws);                       // ROWS*384 bf16 (reused for Y2)
  unsigned short* Y1  = (unsigned short*)(ws + 50331648);            // ROWS*256 bf16
  unsigned short* W0t = (unsigned short*)(ws + 50331648 + 33554432); // 384*256 bf16 (transposed)
  unsigned short* W1t = (unsigned short*)(ws + 50331648 + 33554432 + 196608);
  float* stats = (float*)(ws + 50331648 + 33554432 + 196608 + 131072); // 1024 f32
  int*   idx   = (int*)(stats + 1024);                                 // ROWS*3
  float* wgt   = (float*)(idx + ROWS * 3);                             // ROWS*3
  unsigned short* Y2 = X;  // X buffer free after gemm1

  wt_both<<<640, 256, 0, stream>>>(W0, W1, W0t, W1t, stats);
  nn_kernel<<<BB * (NN / 32), 256, 0, stream>>>(xyz1, xyz2, idx, wgt);
  interp_kernel<<<ROWS / 2, 256, 0, stream>>>(points2, points1, idx, wgt, X);

  gemm_nt<CIN, false><<<1024, 256, 0, stream>>>(X, W0t, Y1, stats, nullptr, nullptr, nullptr);
  gemm_nt<CO, true><<<1024, 256, 0, stream>>>(Y1, W1t, Y2, stats + 512, stats, g0, be0);
  apply_f32<<<(size_t)ROWS * CO / (256 * 8), 256, 0, stream>>>(Y2, stats + 512, g1, be1, out);
}